// Round 4
// baseline (1948.404 us; speedup 1.0000x reference)
//
#include <hip/hip_runtime.h>
#include <cstddef>
#include <cstdint>

#define N_USER 100000
#define N_ITEM 100000
#define N_EDGE 1000000
#define IN_DIM 256
#define HID 128
#define OUT_DIM 16
#define LEAKY_SLOPE 0.01f
#define NBKT 6250        // 100000 / 16 dst rows per bucket
#define SCAN_BLK 25      // ceil(6250/256)

// ---------------------------------------------------------------------------
// C[M,128] = A[M,K] @ W[K,128] + bias   (K multiple of 64; fp32 vector ALU)
// ---------------------------------------------------------------------------
template<int K>
__global__ __launch_bounds__(256)
void gemm_bias_128(const float* __restrict__ A, const float* __restrict__ W,
                   const float* __restrict__ bias, float* __restrict__ C, int M) {
  __shared__ float As[64][68];
  __shared__ float Ws[64][132];
  const int t  = threadIdx.x;
  const int row0 = blockIdx.x * 64;
  const int tx = t & 15;
  const int ty = t >> 4;

  float acc[4][8];
#pragma unroll
  for (int i = 0; i < 4; ++i)
#pragma unroll
    for (int j = 0; j < 8; ++j) acc[i][j] = 0.f;

  const int la_k = t & 15;
  const int la_r = t >> 4;
  const int lw_c = t & 31;
  const int lw_k = t >> 5;

  for (int k0 = 0; k0 < K; k0 += 64) {
    __syncthreads();
#pragma unroll
    for (int p = 0; p < 4; ++p) {
      int r = row0 + la_r + 16 * p;
      r = r < M ? r : M - 1;
      const float4 v = *(const float4*)&A[(size_t)r * K + k0 + la_k * 4];
      As[la_k * 4 + 0][la_r + 16 * p] = v.x;
      As[la_k * 4 + 1][la_r + 16 * p] = v.y;
      As[la_k * 4 + 2][la_r + 16 * p] = v.z;
      As[la_k * 4 + 3][la_r + 16 * p] = v.w;
    }
#pragma unroll
    for (int q = 0; q < 8; ++q) {
      const int kk = lw_k + 8 * q;
      *(float4*)&Ws[kk][lw_c * 4] =
          *(const float4*)&W[(size_t)(k0 + kk) * HID + lw_c * 4];
    }
    __syncthreads();
#pragma unroll 4
    for (int kk = 0; kk < 64; ++kk) {
      const float4 a  = *(const float4*)&As[kk][ty * 4];
      const float4 w0 = *(const float4*)&Ws[kk][tx * 4];
      const float4 w1 = *(const float4*)&Ws[kk][64 + tx * 4];
      const float av[4] = {a.x, a.y, a.z, a.w};
      const float wv[8] = {w0.x, w0.y, w0.z, w0.w, w1.x, w1.y, w1.z, w1.w};
#pragma unroll
      for (int i = 0; i < 4; ++i)
#pragma unroll
        for (int j = 0; j < 8; ++j) acc[i][j] += av[i] * wv[j];
    }
  }

  const float4 b0 = *(const float4*)&bias[tx * 4];
  const float4 b1 = *(const float4*)&bias[64 + tx * 4];
#pragma unroll
  for (int i = 0; i < 4; ++i) {
    const int r = row0 + ty * 4 + i;
    if (r < M) {
      float4 o0 = {acc[i][0] + b0.x, acc[i][1] + b0.y,
                   acc[i][2] + b0.z, acc[i][3] + b0.w};
      float4 o1 = {acc[i][4] + b1.x, acc[i][5] + b1.y,
                   acc[i][6] + b1.z, acc[i][7] + b1.w};
      *(float4*)&C[(size_t)r * HID + tx * 4] = o0;
      *(float4*)&C[(size_t)r * HID + 64 + tx * 4] = o1;
    }
  }
}

// ---------------------------------------------------------------------------
// per-dst degree counts, both relations batched over blockIdx.y
// ---------------------------------------------------------------------------
__global__ __launch_bounds__(256)
void count_deg2(const int* __restrict__ dstA, const int* __restrict__ dstB,
                int* __restrict__ cntA, int* __restrict__ cntB, int n) {
  const int i = blockIdx.x * 256 + threadIdx.x;
  const int* __restrict__ dst = blockIdx.y ? dstB : dstA;
  int* __restrict__ cnt = blockIdx.y ? cntB : cntA;
  if (i < n) atomicAdd(&cnt[dst[i]], 1);
}

// ---------------------------------------------------------------------------
// bucket counts: bcnt[b] = sum of 16 per-dst counts (batched over y)
// ---------------------------------------------------------------------------
__global__ __launch_bounds__(256)
void bucket_sum(const int* __restrict__ cntBase, int* __restrict__ bcntBase) {
  const int b = blockIdx.x * 256 + threadIdx.x;
  if (b >= NBKT) return;
  const int y = blockIdx.y;
  const int4* p = (const int4*)(cntBase + (size_t)y * N_USER + (size_t)b * 16);
  int s = 0;
#pragma unroll
  for (int q = 0; q < 4; ++q) { const int4 v = p[q]; s += v.x + v.y + v.z + v.w; }
  bcntBase[y * NBKT + b] = s;
}

// ---------------------------------------------------------------------------
// 3-phase multi-block exclusive scan over bucket counts (2 relations via y)
// ---------------------------------------------------------------------------
__global__ __launch_bounds__(256)
void scan_p1(const int* __restrict__ cntBase, int n, int* __restrict__ posBase,
             int* __restrict__ bsumBase) {
  __shared__ int sh[256];
  const int y = blockIdx.y, b = blockIdx.x, t = threadIdx.x;
  const int* cnt = cntBase + (size_t)y * n;
  int* pos = posBase + (size_t)y * n;
  int* bsum = bsumBase + (size_t)y * SCAN_BLK;
  const int i = b * 256 + t;
  const int v = (i < n) ? cnt[i] : 0;
  sh[t] = v;
  __syncthreads();
#pragma unroll
  for (int d = 1; d < 256; d <<= 1) {
    const int x = (t >= d) ? sh[t - d] : 0;
    __syncthreads();
    sh[t] += x;
    __syncthreads();
  }
  if (i < n) pos[i] = sh[t] - v;
  if (t == 255) bsum[b] = sh[255];
}

__global__ __launch_bounds__(64)
void scan_p2(int* __restrict__ bsumBase, int nblk) {
  __shared__ int sh[64];
  int* bsum = bsumBase + (size_t)blockIdx.x * SCAN_BLK;
  const int t = threadIdx.x;
  const int v = (t < nblk) ? bsum[t] : 0;
  sh[t] = v;
  __syncthreads();
#pragma unroll
  for (int d = 1; d < 64; d <<= 1) {
    const int x = (t >= d) ? sh[t - d] : 0;
    __syncthreads();
    sh[t] += x;
    __syncthreads();
  }
  if (t < nblk) bsum[t] = sh[t] - v;
}

__global__ __launch_bounds__(256)
void scan_p3(int* __restrict__ posBase, const int* __restrict__ bsumBase, int n) {
  const int y = blockIdx.y;
  int* pos = posBase + (size_t)y * n;
  const int* bsum = bsumBase + (size_t)y * SCAN_BLK;
  const int i = blockIdx.x * 256 + threadIdx.x;
  if (i < n) pos[i] += bsum[blockIdx.x];
}

// ---------------------------------------------------------------------------
// bin edges into 16-dst buckets. Record = src | (dst&15)<<27 (src < 2^17).
// Appends per bucket -> contiguous stores -> no line write-amplification.
// Afterwards boff[b] == bucket end; begin = boff[b] - bcnt[b].
// ---------------------------------------------------------------------------
__global__ __launch_bounds__(256)
void bin_edges(const int* __restrict__ srcA, const int* __restrict__ dstA,
               const int* __restrict__ srcB, const int* __restrict__ dstB,
               int* __restrict__ boff, uint32_t* __restrict__ ebuf, int n) {
  const int e = blockIdx.x * 256 + threadIdx.x;
  if (e >= n) return;
  const int y = blockIdx.y;
  const int* __restrict__ src = y ? srcB : srcA;
  const int* __restrict__ dst = y ? dstB : dstA;
  const int d = dst[e];
  const int p = atomicAdd(&boff[y * NBKT + (d >> 4)], 1);
  ebuf[(size_t)y * N_EDGE + p] = (uint32_t)src[e] | ((uint32_t)(d & 15) << 27);
}

// ---------------------------------------------------------------------------
// bucket aggregate: one block per 16-dst bucket. 16x128 fp32 acc in LDS.
// Half-wave (32 lanes) per edge; lane c covers columns c,c+32,c+64,c+96 so
// LDS atomics are bank-conflict-free (bank == c, 2 lanes/bank per wave64).
// Epilogue: mean (+leaky) and coalesced row writes.
// ---------------------------------------------------------------------------
template<bool DO_LEAKY>
__global__ __launch_bounds__(256)
void bucket_agg(const float* __restrict__ wh, const int* __restrict__ cnt,
                const int* __restrict__ bcnt, const int* __restrict__ boff,
                const uint32_t* __restrict__ ebuf, float* __restrict__ out) {
  __shared__ float acc[16 * HID];   // 8 KB
  const int b = blockIdx.x;
  const int t = threadIdx.x;
#pragma unroll
  for (int k = 0; k < 8; ++k) acc[k * 256 + t] = 0.f;
  __syncthreads();

  const int end = boff[b];
  const int ne  = bcnt[b];
  const int beg = end - ne;
  const int c = t & 31;
  for (int ei = beg + (t >> 5); ei < end; ei += 8) {
    const uint32_t rec = ebuf[ei];
    const int src  = (int)(rec & 0x07FFFFFFu);
    const int dlow = (int)(rec >> 27);
    const float* __restrict__ row = wh + (size_t)src * HID;
    const float w0 = row[c];
    const float w1 = row[c + 32];
    const float w2 = row[c + 64];
    const float w3 = row[c + 96];
    float* arow = acc + dlow * HID;
    atomicAdd(arow + c,      w0);
    atomicAdd(arow + c + 32, w1);
    atomicAdd(arow + c + 64, w2);
    atomicAdd(arow + c + 96, w3);
  }
  __syncthreads();

  const int based = b * 16;
#pragma unroll
  for (int k = 0; k < 8; ++k) {
    const int idx = k * 256 + t;
    const int d = idx >> 7;
    const int cn = cnt[based + d];
    const float inv = cn > 0 ? 1.0f / (float)cn : 0.0f;
    float v = acc[idx] * inv;
    if (DO_LEAKY) v = v > 0.f ? v : LEAKY_SLOPE * v;
    out[(size_t)based * HID + idx] = v;
  }
}

// ---------------------------------------------------------------------------
// out[M,16] = H[M,128] @ W[128,16] + bias
// ---------------------------------------------------------------------------
__global__ __launch_bounds__(256)
void gemm_out16(const float* __restrict__ H, const float* __restrict__ W,
                const float* __restrict__ bias, float* __restrict__ out, int M) {
  __shared__ float Ws[HID * OUT_DIM];
  __shared__ float Hs[16 * HID];
  const int t = threadIdx.x;
  const int row0 = blockIdx.x * 16;
  {
    const float4* s0 = (const float4*)W;
    float4* dp = (float4*)Ws;
    dp[t]       = s0[t];
    dp[t + 256] = s0[t + 256];
    const float4* s1 = (const float4*)(H + (size_t)row0 * HID);
    float4* hp = (float4*)Hs;
    hp[t]       = s1[t];
    hp[t + 256] = s1[t + 256];
  }
  __syncthreads();
  const int r = t >> 4, c = t & 15;
  float s = bias[c];
  const float* h = &Hs[r * HID];
#pragma unroll 8
  for (int k = 0; k < HID; ++k) s += h[k] * Ws[k * OUT_DIM + c];
  out[(size_t)(row0 + r) * OUT_DIM + c] = s;
}

// ---------------------------------------------------------------------------
extern "C" void kernel_launch(void* const* d_in, const int* in_sizes, int n_in,
                              void* d_out, int out_size, void* d_ws, size_t ws_size,
                              hipStream_t stream) {
  const float* feat_user  = (const float*)d_in[0];
  // d_in[1] feat_item : dead (never reaches the output)
  const int*   src_clicks = (const int*)d_in[2];
  const int*   dst_clicks = (const int*)d_in[3];
  const int*   src_cb     = (const int*)d_in[4];
  const int*   dst_cb     = (const int*)d_in[5];
  const float* Win_user   = (const float*)d_in[6];
  const float* bin_user   = (const float*)d_in[7];
  // d_in[8..9] Win_item/bin_item : dead
  const float* W0_clicks  = (const float*)d_in[10];
  const float* b0_clicks  = (const float*)d_in[11];
  // d_in[12..15] W0_cb/b0_cb/W1_clicks/b1_clicks : dead
  const float* W1_cb      = (const float*)d_in[16];
  const float* b1_cb      = (const float*)d_in[17];
  const float* Wout       = (const float*)d_in[18];
  const float* bout       = (const float*)d_in[19];
  float* out = (float*)d_out;

  const size_t SZ = (size_t)N_USER * HID * sizeof(float);  // 51.2 MB each
  char* ws = (char*)d_ws;
  float* buf0 = (float*)ws;                       // x_u -> h_i0 -> h_u1
  float* buf1 = (float*)(ws + SZ);                // wh_u0 -> wh_i1
  int* cnt  = (int*)(ws + 2 * SZ);                // [2][100000] per-dst degree
  int* bcnt = cnt + 2 * N_USER;                   // [2][NBKT]
  int* boff = bcnt + 2 * NBKT;                    // [2][NBKT] (cursor -> end)
  int* bsum = boff + 2 * NBKT;                    // [2][SCAN_BLK]
  uint32_t* ebuf = (uint32_t*)(bsum + 2 * SCAN_BLK + 14);  // [2][N_EDGE]

  const int G64 = (N_USER + 63) / 64;             // 1563
  const int GE  = (N_EDGE + 255) / 256;           // 3907

  // --- bucketed-CSR build for both relations ---
  hipMemsetAsync(cnt, 0, (size_t)2 * N_USER * sizeof(int), stream);
  count_deg2<<<dim3(GE, 2), 256, 0, stream>>>(dst_clicks, dst_cb, cnt, cnt + N_USER, N_EDGE);
  bucket_sum<<<dim3(SCAN_BLK, 2), 256, 0, stream>>>(cnt, bcnt);
  scan_p1<<<dim3(SCAN_BLK, 2), 256, 0, stream>>>(bcnt, NBKT, boff, bsum);
  scan_p2<<<2, 64, 0, stream>>>(bsum, SCAN_BLK);
  scan_p3<<<dim3(SCAN_BLK, 2), 256, 0, stream>>>(boff, bsum, NBKT);
  bin_edges<<<dim3(GE, 2), 256, 0, stream>>>(src_clicks, dst_clicks, src_cb, dst_cb,
                                             boff, ebuf, N_EDGE);

  // 1) x_u = feat_user @ Win_user + bin_user        -> buf0
  gemm_bias_128<IN_DIM><<<G64, 256, 0, stream>>>(feat_user, Win_user, bin_user, buf0, N_USER);
  // 2) wh_u0 = x_u @ W0_clicks + b0_clicks          -> buf1
  gemm_bias_128<HID><<<G64, 256, 0, stream>>>(buf0, W0_clicks, b0_clicks, buf1, N_USER);
  // 3) h_i0 = leaky(seg_mean over clicks)           -> buf0
  bucket_agg<true><<<NBKT, 256, 0, stream>>>(buf1, cnt, bcnt, boff, ebuf, buf0);
  // 4) wh_i1 = h_i0 @ W1_cb + b1_cb                 -> buf1
  gemm_bias_128<HID><<<G64, 256, 0, stream>>>(buf0, W1_cb, b1_cb, buf1, N_ITEM);
  // 5) h_u1 = seg_mean over clicked_by              -> buf0
  bucket_agg<false><<<NBKT, 256, 0, stream>>>(buf1, cnt + N_USER, bcnt + NBKT,
                                              boff + NBKT, ebuf + N_EDGE, buf0);
  // 6) out = h_u1 @ Wout + bout
  gemm_out16<<<N_USER / 16, 256, 0, stream>>>(buf0, Wout, bout, out, N_USER);
}

// Round 5
// 767.235 us; speedup vs baseline: 2.5395x; 2.5395x over previous
//
#include <hip/hip_runtime.h>
#include <cstddef>
#include <cstdint>

#define N_USER 100000
#define N_ITEM 100000
#define N_EDGE 1000000
#define IN_DIM 256
#define HID 128
#define OUT_DIM 16
#define LEAKY_SLOPE 0.01f
#define NBKT 6250        // 100000 / 16 dst rows per bucket
#define SCAN_BLK 25      // ceil(6250/256)

// ---------------------------------------------------------------------------
// C[M,128] = A[M,K] @ W[K,128] + bias   (K multiple of 64; fp32 vector ALU)
// ---------------------------------------------------------------------------
template<int K>
__global__ __launch_bounds__(256)
void gemm_bias_128(const float* __restrict__ A, const float* __restrict__ W,
                   const float* __restrict__ bias, float* __restrict__ C, int M) {
  __shared__ float As[64][68];
  __shared__ float Ws[64][132];
  const int t  = threadIdx.x;
  const int row0 = blockIdx.x * 64;
  const int tx = t & 15;
  const int ty = t >> 4;

  float acc[4][8];
#pragma unroll
  for (int i = 0; i < 4; ++i)
#pragma unroll
    for (int j = 0; j < 8; ++j) acc[i][j] = 0.f;

  const int la_k = t & 15;
  const int la_r = t >> 4;
  const int lw_c = t & 31;
  const int lw_k = t >> 5;

  for (int k0 = 0; k0 < K; k0 += 64) {
    __syncthreads();
#pragma unroll
    for (int p = 0; p < 4; ++p) {
      int r = row0 + la_r + 16 * p;
      r = r < M ? r : M - 1;
      const float4 v = *(const float4*)&A[(size_t)r * K + k0 + la_k * 4];
      As[la_k * 4 + 0][la_r + 16 * p] = v.x;
      As[la_k * 4 + 1][la_r + 16 * p] = v.y;
      As[la_k * 4 + 2][la_r + 16 * p] = v.z;
      As[la_k * 4 + 3][la_r + 16 * p] = v.w;
    }
#pragma unroll
    for (int q = 0; q < 8; ++q) {
      const int kk = lw_k + 8 * q;
      *(float4*)&Ws[kk][lw_c * 4] =
          *(const float4*)&W[(size_t)(k0 + kk) * HID + lw_c * 4];
    }
    __syncthreads();
#pragma unroll 4
    for (int kk = 0; kk < 64; ++kk) {
      const float4 a  = *(const float4*)&As[kk][ty * 4];
      const float4 w0 = *(const float4*)&Ws[kk][tx * 4];
      const float4 w1 = *(const float4*)&Ws[kk][64 + tx * 4];
      const float av[4] = {a.x, a.y, a.z, a.w};
      const float wv[8] = {w0.x, w0.y, w0.z, w0.w, w1.x, w1.y, w1.z, w1.w};
#pragma unroll
      for (int i = 0; i < 4; ++i)
#pragma unroll
        for (int j = 0; j < 8; ++j) acc[i][j] += av[i] * wv[j];
    }
  }

  const float4 b0 = *(const float4*)&bias[tx * 4];
  const float4 b1 = *(const float4*)&bias[64 + tx * 4];
#pragma unroll
  for (int i = 0; i < 4; ++i) {
    const int r = row0 + ty * 4 + i;
    if (r < M) {
      float4 o0 = {acc[i][0] + b0.x, acc[i][1] + b0.y,
                   acc[i][2] + b0.z, acc[i][3] + b0.w};
      float4 o1 = {acc[i][4] + b1.x, acc[i][5] + b1.y,
                   acc[i][6] + b1.z, acc[i][7] + b1.w};
      *(float4*)&C[(size_t)r * HID + tx * 4] = o0;
      *(float4*)&C[(size_t)r * HID + 64 + tx * 4] = o1;
    }
  }
}

// ---------------------------------------------------------------------------
// per-dst degree counts, both relations batched over blockIdx.y
// ---------------------------------------------------------------------------
__global__ __launch_bounds__(256)
void count_deg2(const int* __restrict__ dstA, const int* __restrict__ dstB,
                int* __restrict__ cntA, int* __restrict__ cntB, int n) {
  const int i = blockIdx.x * 256 + threadIdx.x;
  const int* __restrict__ dst = blockIdx.y ? dstB : dstA;
  int* __restrict__ cnt = blockIdx.y ? cntB : cntA;
  if (i < n) atomicAdd(&cnt[dst[i]], 1);
}

// ---------------------------------------------------------------------------
// bucket counts: bcnt[b] = sum of 16 per-dst counts (batched over y)
// ---------------------------------------------------------------------------
__global__ __launch_bounds__(256)
void bucket_sum(const int* __restrict__ cntBase, int* __restrict__ bcntBase) {
  const int b = blockIdx.x * 256 + threadIdx.x;
  if (b >= NBKT) return;
  const int y = blockIdx.y;
  const int4* p = (const int4*)(cntBase + (size_t)y * N_USER + (size_t)b * 16);
  int s = 0;
#pragma unroll
  for (int q = 0; q < 4; ++q) { const int4 v = p[q]; s += v.x + v.y + v.z + v.w; }
  bcntBase[y * NBKT + b] = s;
}

// ---------------------------------------------------------------------------
// 3-phase multi-block exclusive scan over bucket counts (2 relations via y)
// ---------------------------------------------------------------------------
__global__ __launch_bounds__(256)
void scan_p1(const int* __restrict__ cntBase, int n, int* __restrict__ posBase,
             int* __restrict__ bsumBase) {
  __shared__ int sh[256];
  const int y = blockIdx.y, b = blockIdx.x, t = threadIdx.x;
  const int* cnt = cntBase + (size_t)y * n;
  int* pos = posBase + (size_t)y * n;
  int* bsum = bsumBase + (size_t)y * SCAN_BLK;
  const int i = b * 256 + t;
  const int v = (i < n) ? cnt[i] : 0;
  sh[t] = v;
  __syncthreads();
#pragma unroll
  for (int d = 1; d < 256; d <<= 1) {
    const int x = (t >= d) ? sh[t - d] : 0;
    __syncthreads();
    sh[t] += x;
    __syncthreads();
  }
  if (i < n) pos[i] = sh[t] - v;
  if (t == 255) bsum[b] = sh[255];
}

__global__ __launch_bounds__(64)
void scan_p2(int* __restrict__ bsumBase, int nblk) {
  __shared__ int sh[64];
  int* bsum = bsumBase + (size_t)blockIdx.x * SCAN_BLK;
  const int t = threadIdx.x;
  const int v = (t < nblk) ? bsum[t] : 0;
  sh[t] = v;
  __syncthreads();
#pragma unroll
  for (int d = 1; d < 64; d <<= 1) {
    const int x = (t >= d) ? sh[t - d] : 0;
    __syncthreads();
    sh[t] += x;
    __syncthreads();
  }
  if (t < nblk) bsum[t] = sh[t] - v;
}

__global__ __launch_bounds__(256)
void scan_p3(int* __restrict__ posBase, const int* __restrict__ bsumBase, int n) {
  const int y = blockIdx.y;
  int* pos = posBase + (size_t)y * n;
  const int* bsum = bsumBase + (size_t)y * SCAN_BLK;
  const int i = blockIdx.x * 256 + threadIdx.x;
  if (i < n) pos[i] += bsum[blockIdx.x];
}

// ---------------------------------------------------------------------------
// bin edges into 16-dst buckets. Record = src | (dst&15)<<27 (src < 2^17).
// Appends per bucket -> contiguous stores -> no line write-amplification.
// Afterwards boff[b] == bucket end; begin = boff[b] - bcnt[b].
// ---------------------------------------------------------------------------
__global__ __launch_bounds__(256)
void bin_edges(const int* __restrict__ srcA, const int* __restrict__ dstA,
               const int* __restrict__ srcB, const int* __restrict__ dstB,
               int* __restrict__ boff, uint32_t* __restrict__ ebuf, int n) {
  const int e = blockIdx.x * 256 + threadIdx.x;
  if (e >= n) return;
  const int y = blockIdx.y;
  const int* __restrict__ src = y ? srcB : srcA;
  const int* __restrict__ dst = y ? dstB : dstA;
  const int d = dst[e];
  const int p = atomicAdd(&boff[y * NBKT + (d >> 4)], 1);
  ebuf[(size_t)y * N_EDGE + p] = (uint32_t)src[e] | ((uint32_t)(d & 15) << 27);
}

// ---------------------------------------------------------------------------
// in-place intra-bucket counting sort by dlow. One block per bucket.
// Stages the bucket's recs in registers (<=8 per thread; bucket size ~160,
// max ~240 << 2048), then scatters to dst-sorted order via 16 LDS cursors.
// Also emits per-dst row starts: pos[d] = bucket_beg + prefix(cnt within bkt).
// ---------------------------------------------------------------------------
__global__ __launch_bounds__(256)
void bucket_sort(const int* __restrict__ cnt, const int* __restrict__ bcnt,
                 const int* __restrict__ boff, uint32_t* __restrict__ ebufBase,
                 int* __restrict__ pos) {
  __shared__ int scnt[16], pref[16], cur[16];
  const int y = blockIdx.y, b = blockIdx.x, t = threadIdx.x;
  const int end = boff[y * NBKT + b];
  const int ne  = bcnt[y * NBKT + b];
  const int beg = end - ne;
  uint32_t* eb = ebufBase + (size_t)y * N_EDGE;
  if (t < 16) scnt[t] = cnt[(size_t)y * N_USER + b * 16 + t];
  __syncthreads();
  if (t < 16) {
    int p = 0;
    for (int j = 0; j < t; ++j) p += scnt[j];
    pref[t] = p;
    cur[t]  = 0;
    pos[(size_t)y * N_USER + b * 16 + t] = beg + p;
  }
  __syncthreads();
  uint32_t myrec[8];
  int nm = 0;
  for (int i = t; i < ne; i += 256) {
    if (nm < 8) myrec[nm] = eb[beg + i];
    ++nm;
  }
  __syncthreads();
#pragma unroll
  for (int q = 0; q < 8; ++q) {
    if (q < nm) {
      const uint32_t rec = myrec[q];
      const int dlow = (int)(rec >> 27);
      const int slot = atomicAdd(&cur[dlow], 1);
      eb[beg + pref[dlow] + slot] = rec;
    }
  }
}

// ---------------------------------------------------------------------------
// gather segment-mean from dst-sorted rec list. 32 lanes per dst row (float4),
// 8 rows per block. 4-way unrolled so row loads overlap (breaks latency chain).
// ---------------------------------------------------------------------------
template<bool DO_LEAKY>
__global__ __launch_bounds__(256)
void gather_mean(const float* __restrict__ wh, const int* __restrict__ pos,
                 const int* __restrict__ cnt, const uint32_t* __restrict__ ebuf,
                 float* __restrict__ out, int nrows) {
  const int row = blockIdx.x * 8 + (threadIdx.x >> 5);
  if (row >= nrows) return;
  const int c = threadIdx.x & 31;
  const int beg = pos[row];
  const int cn  = cnt[row];
  float4 acc = {0.f, 0.f, 0.f, 0.f};
  int i = 0;
  for (; i + 4 <= cn; i += 4) {
    const int s0 = (int)(ebuf[beg + i]     & 0x07FFFFFFu);
    const int s1 = (int)(ebuf[beg + i + 1] & 0x07FFFFFFu);
    const int s2 = (int)(ebuf[beg + i + 2] & 0x07FFFFFFu);
    const int s3 = (int)(ebuf[beg + i + 3] & 0x07FFFFFFu);
    const float4 v0 = ((const float4*)wh)[(size_t)s0 * 32 + c];
    const float4 v1 = ((const float4*)wh)[(size_t)s1 * 32 + c];
    const float4 v2 = ((const float4*)wh)[(size_t)s2 * 32 + c];
    const float4 v3 = ((const float4*)wh)[(size_t)s3 * 32 + c];
    acc.x += v0.x + v1.x + v2.x + v3.x;
    acc.y += v0.y + v1.y + v2.y + v3.y;
    acc.z += v0.z + v1.z + v2.z + v3.z;
    acc.w += v0.w + v1.w + v2.w + v3.w;
  }
  for (; i < cn; ++i) {
    const int s = (int)(ebuf[beg + i] & 0x07FFFFFFu);
    const float4 v = ((const float4*)wh)[(size_t)s * 32 + c];
    acc.x += v.x; acc.y += v.y; acc.z += v.z; acc.w += v.w;
  }
  const float inv = cn > 0 ? 1.0f / (float)cn : 0.0f;
  acc.x *= inv; acc.y *= inv; acc.z *= inv; acc.w *= inv;
  if (DO_LEAKY) {
    acc.x = acc.x > 0.f ? acc.x : LEAKY_SLOPE * acc.x;
    acc.y = acc.y > 0.f ? acc.y : LEAKY_SLOPE * acc.y;
    acc.z = acc.z > 0.f ? acc.z : LEAKY_SLOPE * acc.z;
    acc.w = acc.w > 0.f ? acc.w : LEAKY_SLOPE * acc.w;
  }
  ((float4*)out)[(size_t)row * 32 + c] = acc;
}

// ---------------------------------------------------------------------------
// out[M,16] = H[M,128] @ W[128,16] + bias
// ---------------------------------------------------------------------------
__global__ __launch_bounds__(256)
void gemm_out16(const float* __restrict__ H, const float* __restrict__ W,
                const float* __restrict__ bias, float* __restrict__ out, int M) {
  __shared__ float Ws[HID * OUT_DIM];
  __shared__ float Hs[16 * HID];
  const int t = threadIdx.x;
  const int row0 = blockIdx.x * 16;
  {
    const float4* s0 = (const float4*)W;
    float4* dp = (float4*)Ws;
    dp[t]       = s0[t];
    dp[t + 256] = s0[t + 256];
    const float4* s1 = (const float4*)(H + (size_t)row0 * HID);
    float4* hp = (float4*)Hs;
    hp[t]       = s1[t];
    hp[t + 256] = s1[t + 256];
  }
  __syncthreads();
  const int r = t >> 4, c = t & 15;
  float s = bias[c];
  const float* h = &Hs[r * HID];
#pragma unroll 8
  for (int k = 0; k < HID; ++k) s += h[k] * Ws[k * OUT_DIM + c];
  out[(size_t)(row0 + r) * OUT_DIM + c] = s;
}

// ---------------------------------------------------------------------------
extern "C" void kernel_launch(void* const* d_in, const int* in_sizes, int n_in,
                              void* d_out, int out_size, void* d_ws, size_t ws_size,
                              hipStream_t stream) {
  const float* feat_user  = (const float*)d_in[0];
  // d_in[1] feat_item : dead (never reaches the output)
  const int*   src_clicks = (const int*)d_in[2];
  const int*   dst_clicks = (const int*)d_in[3];
  const int*   src_cb     = (const int*)d_in[4];
  const int*   dst_cb     = (const int*)d_in[5];
  const float* Win_user   = (const float*)d_in[6];
  const float* bin_user   = (const float*)d_in[7];
  // d_in[8..9] Win_item/bin_item : dead
  const float* W0_clicks  = (const float*)d_in[10];
  const float* b0_clicks  = (const float*)d_in[11];
  // d_in[12..15] W0_cb/b0_cb/W1_clicks/b1_clicks : dead
  const float* W1_cb      = (const float*)d_in[16];
  const float* b1_cb      = (const float*)d_in[17];
  const float* Wout       = (const float*)d_in[18];
  const float* bout       = (const float*)d_in[19];
  float* out = (float*)d_out;

  const size_t SZ = (size_t)N_USER * HID * sizeof(float);  // 51.2 MB each
  char* ws = (char*)d_ws;
  float* buf0 = (float*)ws;                       // x_u -> h_i0 -> h_u1
  float* buf1 = (float*)(ws + SZ);                // wh_u0 -> wh_i1
  int* cnt  = (int*)(ws + 2 * SZ);                // [2][100000] per-dst degree
  int* pos  = cnt + 2 * N_USER;                   // [2][100000] per-dst row beg
  int* bcnt = pos + 2 * N_USER;                   // [2][NBKT]
  int* boff = bcnt + 2 * NBKT;                    // [2][NBKT] (cursor -> end)
  int* bsum = boff + 2 * NBKT;                    // [2][SCAN_BLK]
  uint32_t* ebuf = (uint32_t*)(bsum + 2 * SCAN_BLK + 14);  // [2][N_EDGE]

  const int G64 = (N_USER + 63) / 64;             // 1563
  const int GG  = (N_USER + 7) / 8;               // 12500
  const int GE  = (N_EDGE + 255) / 256;           // 3907

  // --- bucketed dst-sorted edge list for both relations ---
  hipMemsetAsync(cnt, 0, (size_t)2 * N_USER * sizeof(int), stream);
  count_deg2<<<dim3(GE, 2), 256, 0, stream>>>(dst_clicks, dst_cb, cnt, cnt + N_USER, N_EDGE);
  bucket_sum<<<dim3(SCAN_BLK, 2), 256, 0, stream>>>(cnt, bcnt);
  scan_p1<<<dim3(SCAN_BLK, 2), 256, 0, stream>>>(bcnt, NBKT, boff, bsum);
  scan_p2<<<2, 64, 0, stream>>>(bsum, SCAN_BLK);
  scan_p3<<<dim3(SCAN_BLK, 2), 256, 0, stream>>>(boff, bsum, NBKT);
  bin_edges<<<dim3(GE, 2), 256, 0, stream>>>(src_clicks, dst_clicks, src_cb, dst_cb,
                                             boff, ebuf, N_EDGE);
  bucket_sort<<<dim3(NBKT, 2), 256, 0, stream>>>(cnt, bcnt, boff, ebuf, pos);

  // 1) x_u = feat_user @ Win_user + bin_user        -> buf0
  gemm_bias_128<IN_DIM><<<G64, 256, 0, stream>>>(feat_user, Win_user, bin_user, buf0, N_USER);
  // 2) wh_u0 = x_u @ W0_clicks + b0_clicks          -> buf1
  gemm_bias_128<HID><<<G64, 256, 0, stream>>>(buf0, W0_clicks, b0_clicks, buf1, N_USER);
  // 3) h_i0 = leaky(seg_mean over clicks)           -> buf0
  gather_mean<true><<<GG, 256, 0, stream>>>(buf1, pos, cnt, ebuf, buf0, N_ITEM);
  // 4) wh_i1 = h_i0 @ W1_cb + b1_cb                 -> buf1
  gemm_bias_128<HID><<<G64, 256, 0, stream>>>(buf0, W1_cb, b1_cb, buf1, N_ITEM);
  // 5) h_u1 = seg_mean over clicked_by              -> buf0
  gather_mean<false><<<GG, 256, 0, stream>>>(buf1, pos + N_USER, cnt + N_USER,
                                             ebuf + N_EDGE, buf0, N_USER);
  // 6) out = h_u1 @ Wout + bout
  gemm_out16<<<N_USER / 16, 256, 0, stream>>>(buf0, Wout, bout, out, N_USER);
}

// Round 6
// 643.927 us; speedup vs baseline: 3.0258x; 1.1915x over previous
//
#include <hip/hip_runtime.h>
#include <hip/hip_bf16.h>
#include <cstddef>
#include <cstdint>

#define N_USER 100000
#define N_ITEM 100000
#define N_EDGE 1000000
#define IN_DIM 256
#define HID 128
#define OUT_DIM 16
#define LEAKY_SLOPE 0.01f
#define NBKT 6250        // 100000 / 16 dst rows per bucket
#define SCAN_BLK 25      // ceil(6250/256)
#define SRC_MASK 0x07FFFFFFu

static __device__ __forceinline__ unsigned short f2bf(float f) {
  // RTNE bf16 (matches __float2bfloat16 for normal values)
  unsigned int u = __float_as_uint(f);
  u = (u + 0x7FFFu + ((u >> 16) & 1u)) >> 16;
  return (unsigned short)u;
}

// ---------------------------------------------------------------------------
// C[M,128] = A[M,K] @ W[K,128] + bias   (fp32 out) — used for GEMM-A (K=256)
// ---------------------------------------------------------------------------
template<int K>
__global__ __launch_bounds__(256)
void gemm_bias_128(const float* __restrict__ A, const float* __restrict__ W,
                   const float* __restrict__ bias, float* __restrict__ C, int M) {
  __shared__ float As[64][68];
  __shared__ float Ws[64][132];
  const int t  = threadIdx.x;
  const int row0 = blockIdx.x * 64;
  const int tx = t & 15;
  const int ty = t >> 4;

  float acc[4][8];
#pragma unroll
  for (int i = 0; i < 4; ++i)
#pragma unroll
    for (int j = 0; j < 8; ++j) acc[i][j] = 0.f;

  const int la_k = t & 15;
  const int la_r = t >> 4;
  const int lw_c = t & 31;
  const int lw_k = t >> 5;

  for (int k0 = 0; k0 < K; k0 += 64) {
    __syncthreads();
#pragma unroll
    for (int p = 0; p < 4; ++p) {
      int r = row0 + la_r + 16 * p;
      r = r < M ? r : M - 1;
      const float4 v = *(const float4*)&A[(size_t)r * K + k0 + la_k * 4];
      As[la_k * 4 + 0][la_r + 16 * p] = v.x;
      As[la_k * 4 + 1][la_r + 16 * p] = v.y;
      As[la_k * 4 + 2][la_r + 16 * p] = v.z;
      As[la_k * 4 + 3][la_r + 16 * p] = v.w;
    }
#pragma unroll
    for (int q = 0; q < 8; ++q) {
      const int kk = lw_k + 8 * q;
      *(float4*)&Ws[kk][lw_c * 4] =
          *(const float4*)&W[(size_t)(k0 + kk) * HID + lw_c * 4];
    }
    __syncthreads();
#pragma unroll 4
    for (int kk = 0; kk < 64; ++kk) {
      const float4 a  = *(const float4*)&As[kk][ty * 4];
      const float4 w0 = *(const float4*)&Ws[kk][tx * 4];
      const float4 w1 = *(const float4*)&Ws[kk][64 + tx * 4];
      const float av[4] = {a.x, a.y, a.z, a.w};
      const float wv[8] = {w0.x, w0.y, w0.z, w0.w, w1.x, w1.y, w1.z, w1.w};
#pragma unroll
      for (int i = 0; i < 4; ++i)
#pragma unroll
        for (int j = 0; j < 8; ++j) acc[i][j] += av[i] * wv[j];
    }
  }

  const float4 b0 = *(const float4*)&bias[tx * 4];
  const float4 b1 = *(const float4*)&bias[64 + tx * 4];
#pragma unroll
  for (int i = 0; i < 4; ++i) {
    const int r = row0 + ty * 4 + i;
    if (r < M) {
      float4 o0 = {acc[i][0] + b0.x, acc[i][1] + b0.y,
                   acc[i][2] + b0.z, acc[i][3] + b0.w};
      float4 o1 = {acc[i][4] + b1.x, acc[i][5] + b1.y,
                   acc[i][6] + b1.z, acc[i][7] + b1.w};
      *(float4*)&C[(size_t)r * HID + tx * 4] = o0;
      *(float4*)&C[(size_t)r * HID + 64 + tx * 4] = o1;
    }
  }
}

// ---------------------------------------------------------------------------
// GEMM-B: Cb[M,128](bf16) = A[M,128] @ W[128,128] + bias  (fp32 math, bf16 out)
// ---------------------------------------------------------------------------
__global__ __launch_bounds__(256)
void gemm_bias_128_bf16(const float* __restrict__ A, const float* __restrict__ W,
                        const float* __restrict__ bias,
                        unsigned short* __restrict__ Cb, int M) {
  __shared__ float As[64][68];
  __shared__ float Ws[64][132];
  const int t  = threadIdx.x;
  const int row0 = blockIdx.x * 64;
  const int tx = t & 15;
  const int ty = t >> 4;

  float acc[4][8];
#pragma unroll
  for (int i = 0; i < 4; ++i)
#pragma unroll
    for (int j = 0; j < 8; ++j) acc[i][j] = 0.f;

  const int la_k = t & 15;
  const int la_r = t >> 4;
  const int lw_c = t & 31;
  const int lw_k = t >> 5;

  for (int k0 = 0; k0 < HID; k0 += 64) {
    __syncthreads();
#pragma unroll
    for (int p = 0; p < 4; ++p) {
      int r = row0 + la_r + 16 * p;
      r = r < M ? r : M - 1;
      const float4 v = *(const float4*)&A[(size_t)r * HID + k0 + la_k * 4];
      As[la_k * 4 + 0][la_r + 16 * p] = v.x;
      As[la_k * 4 + 1][la_r + 16 * p] = v.y;
      As[la_k * 4 + 2][la_r + 16 * p] = v.z;
      As[la_k * 4 + 3][la_r + 16 * p] = v.w;
    }
#pragma unroll
    for (int q = 0; q < 8; ++q) {
      const int kk = lw_k + 8 * q;
      *(float4*)&Ws[kk][lw_c * 4] =
          *(const float4*)&W[(size_t)(k0 + kk) * HID + lw_c * 4];
    }
    __syncthreads();
#pragma unroll 4
    for (int kk = 0; kk < 64; ++kk) {
      const float4 a  = *(const float4*)&As[kk][ty * 4];
      const float4 w0 = *(const float4*)&Ws[kk][tx * 4];
      const float4 w1 = *(const float4*)&Ws[kk][64 + tx * 4];
      const float av[4] = {a.x, a.y, a.z, a.w};
      const float wv[8] = {w0.x, w0.y, w0.z, w0.w, w1.x, w1.y, w1.z, w1.w};
#pragma unroll
      for (int i = 0; i < 4; ++i)
#pragma unroll
        for (int j = 0; j < 8; ++j) acc[i][j] += av[i] * wv[j];
    }
  }

  const float4 b0 = *(const float4*)&bias[tx * 4];
  const float4 b1 = *(const float4*)&bias[64 + tx * 4];
#pragma unroll
  for (int i = 0; i < 4; ++i) {
    const int r = row0 + ty * 4 + i;
    if (r < M) {
      ushort4 p0, p1;
      p0.x = f2bf(acc[i][0] + b0.x); p0.y = f2bf(acc[i][1] + b0.y);
      p0.z = f2bf(acc[i][2] + b0.z); p0.w = f2bf(acc[i][3] + b0.w);
      p1.x = f2bf(acc[i][4] + b1.x); p1.y = f2bf(acc[i][5] + b1.y);
      p1.z = f2bf(acc[i][6] + b1.z); p1.w = f2bf(acc[i][7] + b1.w);
      *(ushort4*)&Cb[(size_t)r * HID + tx * 4] = p0;
      *(ushort4*)&Cb[(size_t)r * HID + 64 + tx * 4] = p1;
    }
  }
}

// ---------------------------------------------------------------------------
// per-dst degree counts, both relations batched over blockIdx.y
// ---------------------------------------------------------------------------
__global__ __launch_bounds__(256)
void count_deg2(const int* __restrict__ dstA, const int* __restrict__ dstB,
                int* __restrict__ cntA, int* __restrict__ cntB, int n) {
  const int i = blockIdx.x * 256 + threadIdx.x;
  const int* __restrict__ dst = blockIdx.y ? dstB : dstA;
  int* __restrict__ cnt = blockIdx.y ? cntB : cntA;
  if (i < n) atomicAdd(&cnt[dst[i]], 1);
}

// ---------------------------------------------------------------------------
// bucket counts: bcnt[b] = sum of 16 per-dst counts (batched over y)
// ---------------------------------------------------------------------------
__global__ __launch_bounds__(256)
void bucket_sum(const int* __restrict__ cntBase, int* __restrict__ bcntBase) {
  const int b = blockIdx.x * 256 + threadIdx.x;
  if (b >= NBKT) return;
  const int y = blockIdx.y;
  const int4* p = (const int4*)(cntBase + (size_t)y * N_USER + (size_t)b * 16);
  int s = 0;
#pragma unroll
  for (int q = 0; q < 4; ++q) { const int4 v = p[q]; s += v.x + v.y + v.z + v.w; }
  bcntBase[y * NBKT + b] = s;
}

// ---------------------------------------------------------------------------
// 3-phase multi-block exclusive scan over bucket counts (2 relations via y)
// ---------------------------------------------------------------------------
__global__ __launch_bounds__(256)
void scan_p1(const int* __restrict__ cntBase, int n, int* __restrict__ posBase,
             int* __restrict__ bsumBase) {
  __shared__ int sh[256];
  const int y = blockIdx.y, b = blockIdx.x, t = threadIdx.x;
  const int* cnt = cntBase + (size_t)y * n;
  int* pos = posBase + (size_t)y * n;
  int* bsum = bsumBase + (size_t)y * SCAN_BLK;
  const int i = b * 256 + t;
  const int v = (i < n) ? cnt[i] : 0;
  sh[t] = v;
  __syncthreads();
#pragma unroll
  for (int d = 1; d < 256; d <<= 1) {
    const int x = (t >= d) ? sh[t - d] : 0;
    __syncthreads();
    sh[t] += x;
    __syncthreads();
  }
  if (i < n) pos[i] = sh[t] - v;
  if (t == 255) bsum[b] = sh[255];
}

__global__ __launch_bounds__(64)
void scan_p2(int* __restrict__ bsumBase, int nblk) {
  __shared__ int sh[64];
  int* bsum = bsumBase + (size_t)blockIdx.x * SCAN_BLK;
  const int t = threadIdx.x;
  const int v = (t < nblk) ? bsum[t] : 0;
  sh[t] = v;
  __syncthreads();
#pragma unroll
  for (int d = 1; d < 64; d <<= 1) {
    const int x = (t >= d) ? sh[t - d] : 0;
    __syncthreads();
    sh[t] += x;
    __syncthreads();
  }
  if (t < nblk) bsum[t] = sh[t] - v;
}

__global__ __launch_bounds__(256)
void scan_p3(int* __restrict__ posBase, const int* __restrict__ bsumBase, int n) {
  const int y = blockIdx.y;
  int* pos = posBase + (size_t)y * n;
  const int* bsum = bsumBase + (size_t)y * SCAN_BLK;
  const int i = blockIdx.x * 256 + threadIdx.x;
  if (i < n) pos[i] += bsum[blockIdx.x];
}

// ---------------------------------------------------------------------------
// bin edges into 16-dst buckets. Record = src | (dst&15)<<27.
// ---------------------------------------------------------------------------
__global__ __launch_bounds__(256)
void bin_edges(const int* __restrict__ srcA, const int* __restrict__ dstA,
               const int* __restrict__ srcB, const int* __restrict__ dstB,
               int* __restrict__ boff, uint32_t* __restrict__ ebuf, int n) {
  const int e = blockIdx.x * 256 + threadIdx.x;
  if (e >= n) return;
  const int y = blockIdx.y;
  const int* __restrict__ src = y ? srcB : srcA;
  const int* __restrict__ dst = y ? dstB : dstA;
  const int d = dst[e];
  const int p = atomicAdd(&boff[y * NBKT + (d >> 4)], 1);
  ebuf[(size_t)y * N_EDGE + p] = (uint32_t)src[e] | ((uint32_t)(d & 15) << 27);
}

// ---------------------------------------------------------------------------
// in-place intra-bucket counting sort by dlow; emits per-dst row starts.
// ---------------------------------------------------------------------------
__global__ __launch_bounds__(256)
void bucket_sort(const int* __restrict__ cnt, const int* __restrict__ bcnt,
                 const int* __restrict__ boff, uint32_t* __restrict__ ebufBase,
                 int* __restrict__ pos) {
  __shared__ int scnt[16], pref[16], cur[16];
  const int y = blockIdx.y, b = blockIdx.x, t = threadIdx.x;
  const int end = boff[y * NBKT + b];
  const int ne  = bcnt[y * NBKT + b];
  const int beg = end - ne;
  uint32_t* eb = ebufBase + (size_t)y * N_EDGE;
  if (t < 16) scnt[t] = cnt[(size_t)y * N_USER + b * 16 + t];
  __syncthreads();
  if (t < 16) {
    int p = 0;
    for (int j = 0; j < t; ++j) p += scnt[j];
    pref[t] = p;
    cur[t]  = 0;
    pos[(size_t)y * N_USER + b * 16 + t] = beg + p;
  }
  __syncthreads();
  uint32_t myrec[8];
  int nm = 0;
  for (int i = t; i < ne; i += 256) {
    if (nm < 8) myrec[nm] = eb[beg + i];
    ++nm;
  }
  __syncthreads();
#pragma unroll
  for (int q = 0; q < 8; ++q) {
    if (q < nm) {
      const uint32_t rec = myrec[q];
      const int dlow = (int)(rec >> 27);
      const int slot = atomicAdd(&cur[dlow], 1);
      eb[beg + pref[dlow] + slot] = rec;
    }
  }
}

// ---------------------------------------------------------------------------
// Wfuse[128,16] = W1 @ Wout ; bfuse[16] = b1 @ Wout + bout. One block.
// ---------------------------------------------------------------------------
__global__ __launch_bounds__(256)
void make_wfuse(const float* __restrict__ W1, const float* __restrict__ b1,
                const float* __restrict__ Wout, const float* __restrict__ bout,
                float* __restrict__ Wf, float* __restrict__ bf) {
  __shared__ float Ws[HID * OUT_DIM];
  const int t = threadIdx.x;
  {
    const float4* s0 = (const float4*)Wout;
    float4* dp = (float4*)Ws;
    dp[t]       = s0[t];
    dp[t + 256] = s0[t + 256];
  }
  __syncthreads();
  const int k  = t >> 1;
  const int j0 = (t & 1) * 8;
  const float* w1row = W1 + (size_t)k * HID;
  float acc[8] = {0.f, 0.f, 0.f, 0.f, 0.f, 0.f, 0.f, 0.f};
  for (int m = 0; m < HID; ++m) {
    const float a = w1row[m];
    const float* wr = &Ws[m * OUT_DIM + j0];
#pragma unroll
    for (int q = 0; q < 8; ++q) acc[q] += a * wr[q];
  }
#pragma unroll
  for (int q = 0; q < 8; ++q) Wf[(size_t)k * OUT_DIM + j0 + q] = acc[q];
  if (t < OUT_DIM) {
    float s = bout[t];
    for (int m = 0; m < HID; ++m) s += b1[m] * Ws[m * OUT_DIM + t];
    bf[t] = s;
  }
}

// ---------------------------------------------------------------------------
// gather-1: h[d,128](fp32) = leaky(mean over edges of bf16 wh rows).
// 16 lanes per dst row (uint4 = 8 bf16 each), 16 rows per block, 4-way unroll.
// ---------------------------------------------------------------------------
static __device__ __forceinline__ void acc_bf8(float* a, uint4 u) {
  a[0] += __uint_as_float(u.x << 16);
  a[1] += __uint_as_float(u.x & 0xffff0000u);
  a[2] += __uint_as_float(u.y << 16);
  a[3] += __uint_as_float(u.y & 0xffff0000u);
  a[4] += __uint_as_float(u.z << 16);
  a[5] += __uint_as_float(u.z & 0xffff0000u);
  a[6] += __uint_as_float(u.w << 16);
  a[7] += __uint_as_float(u.w & 0xffff0000u);
}

__global__ __launch_bounds__(256)
void gather_mean_bf16(const unsigned short* __restrict__ bh,
                      const int* __restrict__ pos, const int* __restrict__ cnt,
                      const uint32_t* __restrict__ ebuf, float* __restrict__ out) {
  const int row = blockIdx.x * 16 + (threadIdx.x >> 4);
  const int c = threadIdx.x & 15;
  const int beg = pos[row];
  const int cn  = cnt[row];
  float acc[8] = {0.f, 0.f, 0.f, 0.f, 0.f, 0.f, 0.f, 0.f};
  int i = 0;
  for (; i + 4 <= cn; i += 4) {
    const int s0 = (int)(ebuf[beg + i]     & SRC_MASK);
    const int s1 = (int)(ebuf[beg + i + 1] & SRC_MASK);
    const int s2 = (int)(ebuf[beg + i + 2] & SRC_MASK);
    const int s3 = (int)(ebuf[beg + i + 3] & SRC_MASK);
    const uint4 v0 = *((const uint4*)(bh + (size_t)s0 * HID) + c);
    const uint4 v1 = *((const uint4*)(bh + (size_t)s1 * HID) + c);
    const uint4 v2 = *((const uint4*)(bh + (size_t)s2 * HID) + c);
    const uint4 v3 = *((const uint4*)(bh + (size_t)s3 * HID) + c);
    acc_bf8(acc, v0); acc_bf8(acc, v1); acc_bf8(acc, v2); acc_bf8(acc, v3);
  }
  for (; i < cn; ++i) {
    const int s = (int)(ebuf[beg + i] & SRC_MASK);
    const uint4 v = *((const uint4*)(bh + (size_t)s * HID) + c);
    acc_bf8(acc, v);
  }
  const float inv = cn > 0 ? 1.0f / (float)cn : 0.0f;
  float4 o0, o1;
  float r[8];
#pragma unroll
  for (int q = 0; q < 8; ++q) {
    float v = acc[q] * inv;
    r[q] = v > 0.f ? v : LEAKY_SLOPE * v;
  }
  o0 = make_float4(r[0], r[1], r[2], r[3]);
  o1 = make_float4(r[4], r[5], r[6], r[7]);
  float* op = out + (size_t)row * HID + c * 8;
  *(float4*)op = o0;
  *(float4*)(op + 4) = o1;
}

// ---------------------------------------------------------------------------
// z[M,16] = H[M,128] @ Wf[128,16]   (no bias)
// ---------------------------------------------------------------------------
__global__ __launch_bounds__(256)
void gemm_z16(const float* __restrict__ H, const float* __restrict__ Wf,
              float* __restrict__ z, int M) {
  __shared__ float Ws[HID * OUT_DIM];
  __shared__ float Hs[16 * HID];
  const int t = threadIdx.x;
  const int row0 = blockIdx.x * 16;
  {
    const float4* s0 = (const float4*)Wf;
    float4* dp = (float4*)Ws;
    dp[t]       = s0[t];
    dp[t + 256] = s0[t + 256];
    const float4* s1 = (const float4*)(H + (size_t)row0 * HID);
    float4* hp = (float4*)Hs;
    hp[t]       = s1[t];
    hp[t + 256] = s1[t + 256];
  }
  __syncthreads();
  const int r = t >> 4, c = t & 15;
  float s = 0.f;
  const float* h = &Hs[r * HID];
#pragma unroll 8
  for (int k = 0; k < HID; ++k) s += h[k] * Ws[k * OUT_DIM + c];
  z[(size_t)(row0 + r) * OUT_DIM + c] = s;
}

// ---------------------------------------------------------------------------
// gather-2: out[d,16] = mean(z[src]) + (cn>0 ? bfuse : bout)
// 16 lanes per dst row (one float each), 16 rows per block, 4-way unroll.
// ---------------------------------------------------------------------------
__global__ __launch_bounds__(256)
void gather_mean16(const float* __restrict__ z, const int* __restrict__ pos,
                   const int* __restrict__ cnt, const uint32_t* __restrict__ ebuf,
                   const float* __restrict__ bfuse, const float* __restrict__ bout,
                   float* __restrict__ out) {
  const int row = blockIdx.x * 16 + (threadIdx.x >> 4);
  const int c = threadIdx.x & 15;
  const int beg = pos[row];
  const int cn  = cnt[row];
  float acc = 0.f;
  int i = 0;
  for (; i + 4 <= cn; i += 4) {
    const int s0 = (int)(ebuf[beg + i]     & SRC_MASK);
    const int s1 = (int)(ebuf[beg + i + 1] & SRC_MASK);
    const int s2 = (int)(ebuf[beg + i + 2] & SRC_MASK);
    const int s3 = (int)(ebuf[beg + i + 3] & SRC_MASK);
    const float v0 = z[(size_t)s0 * OUT_DIM + c];
    const float v1 = z[(size_t)s1 * OUT_DIM + c];
    const float v2 = z[(size_t)s2 * OUT_DIM + c];
    const float v3 = z[(size_t)s3 * OUT_DIM + c];
    acc += v0 + v1 + v2 + v3;
  }
  for (; i < cn; ++i) {
    const int s = (int)(ebuf[beg + i] & SRC_MASK);
    acc += z[(size_t)s * OUT_DIM + c];
  }
  float o;
  if (cn > 0) o = acc * (1.0f / (float)cn) + bfuse[c];
  else        o = bout[c];
  out[(size_t)row * OUT_DIM + c] = o;
}

// ---------------------------------------------------------------------------
extern "C" void kernel_launch(void* const* d_in, const int* in_sizes, int n_in,
                              void* d_out, int out_size, void* d_ws, size_t ws_size,
                              hipStream_t stream) {
  const float* feat_user  = (const float*)d_in[0];
  // d_in[1] feat_item : dead (never reaches the output)
  const int*   src_clicks = (const int*)d_in[2];
  const int*   dst_clicks = (const int*)d_in[3];
  const int*   src_cb     = (const int*)d_in[4];
  const int*   dst_cb     = (const int*)d_in[5];
  const float* Win_user   = (const float*)d_in[6];
  const float* bin_user   = (const float*)d_in[7];
  // d_in[8..9] Win_item/bin_item : dead
  const float* W0_clicks  = (const float*)d_in[10];
  const float* b0_clicks  = (const float*)d_in[11];
  // d_in[12..15] W0_cb/b0_cb/W1_clicks/b1_clicks : dead
  const float* W1_cb      = (const float*)d_in[16];
  const float* b1_cb      = (const float*)d_in[17];
  const float* Wout       = (const float*)d_in[18];
  const float* bout       = (const float*)d_in[19];
  float* out = (float*)d_out;

  const size_t SZ  = (size_t)N_USER * HID * sizeof(float);           // 51.2 MB
  const size_t SZH = (size_t)N_USER * HID * sizeof(unsigned short);  // 25.6 MB
  const size_t SZZ = (size_t)N_USER * OUT_DIM * sizeof(float);       // 6.4 MB
  char* ws = (char*)d_ws;
  float* buf0          = (float*)ws;                   // x_u -> h_i0
  unsigned short* bh   = (unsigned short*)(ws + SZ);   // wh_u0 (bf16)
  float* z0            = (float*)(ws + SZ + SZH);      // h_i0 @ Wfuse
  float* Wf            = (float*)(ws + SZ + SZH + SZZ);        // [128,16]
  float* bf            = Wf + HID * OUT_DIM;                   // [16]
  int* cnt  = (int*)(bf + OUT_DIM);               // [2][100000] per-dst degree
  int* pos  = cnt + 2 * N_USER;                   // [2][100000] per-dst row beg
  int* bcnt = pos + 2 * N_USER;                   // [2][NBKT]
  int* boff = bcnt + 2 * NBKT;                    // [2][NBKT]
  int* bsum = boff + 2 * NBKT;                    // [2][SCAN_BLK]
  uint32_t* ebuf = (uint32_t*)(bsum + 2 * SCAN_BLK + 14);  // [2][N_EDGE]

  const int G64 = (N_USER + 63) / 64;             // 1563
  const int G16 = N_USER / 16;                    // 6250
  const int GE  = (N_EDGE + 255) / 256;           // 3907

  // --- bucketed dst-sorted edge list for both relations ---
  hipMemsetAsync(cnt, 0, (size_t)2 * N_USER * sizeof(int), stream);
  count_deg2<<<dim3(GE, 2), 256, 0, stream>>>(dst_clicks, dst_cb, cnt, cnt + N_USER, N_EDGE);
  bucket_sum<<<dim3(SCAN_BLK, 2), 256, 0, stream>>>(cnt, bcnt);
  scan_p1<<<dim3(SCAN_BLK, 2), 256, 0, stream>>>(bcnt, NBKT, boff, bsum);
  scan_p2<<<2, 64, 0, stream>>>(bsum, SCAN_BLK);
  scan_p3<<<dim3(SCAN_BLK, 2), 256, 0, stream>>>(boff, bsum, NBKT);
  bin_edges<<<dim3(GE, 2), 256, 0, stream>>>(src_clicks, dst_clicks, src_cb, dst_cb,
                                             boff, ebuf, N_EDGE);
  bucket_sort<<<dim3(NBKT, 2), 256, 0, stream>>>(cnt, bcnt, boff, ebuf, pos);

  // fused final projection: Wf = W1_cb @ Wout, bf = b1_cb @ Wout + bout
  make_wfuse<<<1, 256, 0, stream>>>(W1_cb, b1_cb, Wout, bout, Wf, bf);

  // 1) x_u = feat_user @ Win_user + bin_user            -> buf0 (fp32)
  gemm_bias_128<IN_DIM><<<G64, 256, 0, stream>>>(feat_user, Win_user, bin_user, buf0, N_USER);
  // 2) wh_u0 = x_u @ W0_clicks + b0_clicks              -> bh (bf16)
  gemm_bias_128_bf16<<<G64, 256, 0, stream>>>(buf0, W0_clicks, b0_clicks, bh, N_USER);
  // 3) h_i0 = leaky(seg_mean over clicks)               -> buf0 (fp32)
  gather_mean_bf16<<<G16, 256, 0, stream>>>(bh, pos, cnt, ebuf, buf0);
  // 4) z0 = h_i0 @ (W1_cb @ Wout)                       -> z0
  gemm_z16<<<G16, 256, 0, stream>>>(buf0, Wf, z0, N_ITEM);
  // 5) out = seg_mean(z0 over clicked_by) + bias select -> out
  gather_mean16<<<G16, 256, 0, stream>>>(z0, pos + N_USER, cnt + N_USER,
                                         ebuf + N_EDGE, bf, bout, out);
}